// Round 1
// baseline (446.769 us; speedup 1.0000x reference)
//
#include <hip/hip_runtime.h>
#include <cmath>

#define THREADS 256
#define MTASKS  144   // mask (b,s) tasks per block: 144*132B = 19008 B LDS
#define GROWS   12    // geo rows per block: 12*1584B = 19008 B LDS (same buffer)
#define SLOTS   64    // accumulator spreading to avoid same-address atomic serialization

struct Tables { float cont[13]; float cw[12]; float ew[12]; };

static Tables make_tables() {
    Tables tb;
    tb.cont[0] = 0.0f;
    for (int j = 1; j <= 12; j++) {
        // numpy: x = linspace(0, b, 2000) (step b/1999), dx = b/2000
        double b = (double)j;
        double s = 0.0;
        for (int k = 0; k < 2000; k++) {
            double x = b * (double)k / 1999.0;
            s += pow(0.8, x);
        }
        double integ = s * (b / 2000.0);
        tb.cont[j] = (float)(1.0 / integ);
    }
    for (int s = 0; s < 12; s++) {
        double w = pow(0.8, (double)s);
        tb.cw[s] = (float)w;
        tb.ew[s] = (float)(w + 1.0);
    }
    return tb;
}

__global__ void zero_acc(double* g) {
    int t = threadIdx.x;
    if (t < 5 * SLOTS) g[t] = 0.0;
}

// LDS budget: buf 19008 + s_ce 576 + s_corr 576 + tables 148 + red 48 ≈ 20356 B
// → rounds to 20480 B = 160 KiB / 8  → 8 blocks/CU = 32 waves = 100% occupancy
__global__ __launch_bounds__(THREADS, 8) void loss_fused(
    const float* __restrict__ geo,   // (B,12,33)
    const float* __restrict__ mgo,   // (B,13,33)
    const int*   __restrict__ pos,   // (B,13)
    const int*   __restrict__ mgt,   // (B,13)
    double*      __restrict__ gacc,  // 5 * SLOTS doubles
    int B, int geoBlocks, Tables tb)
{
    __shared__ float buf[4752];            // 19008 B, shared by both block types
    __shared__ float s_ce[GROWS * 12];
    __shared__ int   s_corr[GROWS * 12];
    __shared__ float sh_cont[13];
    __shared__ float sh_cw[12];
    __shared__ float sh_ew[12];
    __shared__ float red[4][3];

    const int t = threadIdx.x;
    float v0 = 0.0f, v1 = 0.0f, v2 = 0.0f;
    const bool isGeo = (blockIdx.x < (unsigned)geoBlocks);

    if (isGeo) {
        const long long row0 = (long long)blockIdx.x * GROWS;
        const int nrows = min(GROWS, (int)(B - row0));
        const int ntask = nrows * 12;
        const int r = t / 12, s = t - (t / 12) * 12;
        // hoist target load above staging: global latency overlaps the float4 stage
        int tg = 0;
        if (t < ntask) tg = pos[(row0 + r) * 13 + s + 1];
        // copy tables to LDS with STATIC indices only (dynamic kernarg index would spill)
        if (t == 0) {
            #pragma unroll
            for (int j = 0; j < 13; j++) sh_cont[j] = tb.cont[j];
            #pragma unroll
            for (int j = 0; j < 12; j++) { sh_cw[j] = tb.cw[j]; sh_ew[j] = tb.ew[j]; }
        }
        {   // stage nrows*396 floats, fully coalesced float4 (1584 B/row, 16B-aligned)
            const float4* src4 = reinterpret_cast<const float4*>(geo + row0 * 396);
            float4* dst4 = reinterpret_cast<float4*>(buf);
            const int nf4 = nrows * 99;   // nrows*396/4
            for (int i = t; i < nf4; i += THREADS) dst4[i] = src4[i];
        }
        __syncthreads();

        if (t < ntask) {
            const float* x = buf + r * 396 + s * 33;
            float xv[33];
            #pragma unroll
            for (int k = 0; k < 33; k++) xv[k] = x[k];   // static idx -> registers
            float m = xv[0]; int am = 0;
            #pragma unroll
            for (int k = 1; k < 33; k++) { if (xv[k] > m) { m = xv[k]; am = k; } }
            float sum = 0.0f;
            #pragma unroll
            for (int k = 0; k < 33; k++) sum += __expf(xv[k] - m);
            float lse = __logf(sum) + m;
            int tc = tg < 0 ? 0 : (tg > 32 ? 32 : tg);
            float xtc = 0.0f;
            #pragma unroll
            for (int k = 0; k < 33; k++) { if (k == tc) xtc = xv[k]; }  // predicated, no spill
            float ce = (tg == 32) ? 0.0f : (lse - xtc);   // ignore_index = 32
            bool corr = (am == tg);
            v1 = corr ? ce * sh_cw[s] : 0.0f;
            v2 = corr ? 0.0f : ce * sh_ew[s];
            s_ce[t] = ce;
            s_corr[t] = corr ? 1 : 0;
        }
        __syncthreads();

        // per-row prefix: first-incorrect index + weighted prefix sum
        if (t < nrows) {
            float ps = 0.0f; int mi = 12;
            for (int s2 = 0; s2 < 12; s2++) {
                if (!s_corr[t * 12 + s2]) { mi = s2; break; }
                ps += s_ce[t * 12 + s2];
            }
            v0 = (mi >= 12) ? 0.0f : ps * sh_cont[mi];   // all-correct: cont idx 0 -> 0
        }
    } else {
        const long long totalTasks = (long long)B * 13;
        const long long base = (long long)(blockIdx.x - geoBlocks) * MTASKS;
        const int cnt = (int)min((long long)MTASKS, totalTasks - base);
        // hoist target load above staging
        int tg = 0;
        if (t < cnt) tg = mgt[base + t];
        {   // stage cnt*33 floats (base byte = base*132, 16B-aligned since base%144==0 -> %4==0)
            const float* src = mgo + base * 33;
            const int nf = cnt * 33, nf4 = nf >> 2;
            const float4* src4 = reinterpret_cast<const float4*>(src);
            float4* dst4 = reinterpret_cast<float4*>(buf);
            for (int i = t; i < nf4; i += THREADS) dst4[i] = src4[i];
            for (int i = (nf4 << 2) + t; i < nf; i += THREADS) buf[i] = src[i];
        }
        __syncthreads();

        if (t < cnt) {
            const float* x = buf + t * 33;
            float xv[33];
            #pragma unroll
            for (int k = 0; k < 33; k++) xv[k] = x[k];
            float m = xv[0];
            #pragma unroll
            for (int k = 1; k < 33; k++) m = fmaxf(m, xv[k]);
            float sum = 0.0f;
            #pragma unroll
            for (int k = 0; k < 33; k++) sum += __expf(xv[k] - m);
            float lse = __logf(sum) + m;
            int tc = tg < 0 ? 0 : (tg > 32 ? 32 : tg);
            float xtc = 0.0f;
            #pragma unroll
            for (int k = 0; k < 33; k++) { if (k == tc) xtc = xv[k]; }
            if (tg != -100) { v0 = lse - xtc; v1 = 1.0f; }
        }
    }

    // block reduction: wave64 shuffle then cross-wave via LDS
    #pragma unroll
    for (int off = 32; off; off >>= 1) {
        v0 += __shfl_down(v0, off, 64);
        v1 += __shfl_down(v1, off, 64);
        v2 += __shfl_down(v2, off, 64);
    }
    const int wid = t >> 6, lane = t & 63;
    if (lane == 0) { red[wid][0] = v0; red[wid][1] = v1; red[wid][2] = v2; }
    __syncthreads();
    if (t == 0) {
        float a0 = 0, a1 = 0, a2 = 0;
        for (int w = 0; w < 4; w++) { a0 += red[w][0]; a1 += red[w][1]; a2 += red[w][2]; }
        const int slot = blockIdx.x & (SLOTS - 1);
        if (isGeo) {
            atomicAdd(&gacc[2 * SLOTS + slot], (double)a0);
            atomicAdd(&gacc[3 * SLOTS + slot], (double)a1);
            atomicAdd(&gacc[4 * SLOTS + slot], (double)a2);
        } else {
            atomicAdd(&gacc[0 * SLOTS + slot], (double)a0);
            atomicAdd(&gacc[1 * SLOTS + slot], (double)a1);
        }
    }
}

__global__ void finalize(const double* __restrict__ g,
                         const float* __restrict__ aux,
                         const float* __restrict__ taux,
                         const float* __restrict__ sigma,
                         float* __restrict__ out, double denom)
{
    const int i = threadIdx.x;   // 64 threads
    double a[5];
    #pragma unroll
    for (int q = 0; q < 5; q++) a[q] = g[q * SLOTS + i];
    #pragma unroll
    for (int off = 32; off; off >>= 1) {
        #pragma unroll
        for (int q = 0; q < 5; q++) a[q] += __shfl_down(a[q], off, 64);
    }
    if (i == 0) {
        double mask_loss = a[0] / fmax(a[1], 1.0);
        double prefix = a[2] / denom, corrL = a[3] / denom, errL = a[4] / denom;
        double geoL = prefix + corrL + errL;
        double L[4] = { geoL, mask_loss, (double)aux[0], (double)taux[0] };
        double wsum = 0.0, prod = 1.0;
        for (int q = 0; q < 4; q++) {
            double sg = (double)sigma[q];
            wsum += 0.5 * L[q] / (sg * sg);
            prod *= sg;
        }
        wsum += log(prod);
        out[0] = (float)wsum;
        out[1] = (float)prefix;
        out[2] = (float)corrL;
        out[3] = (float)errL;
        out[4] = (float)mask_loss;
    }
}

extern "C" void kernel_launch(void* const* d_in, const int* in_sizes, int n_in,
                              void* d_out, int out_size, void* d_ws, size_t ws_size,
                              hipStream_t stream)
{
    static Tables tb = make_tables();   // host-only, graph-capture safe

    const float* geo   = (const float*)d_in[0];
    const float* mgo   = (const float*)d_in[1];
    const int*   pos   = (const int*)d_in[2];
    const int*   mgt   = (const int*)d_in[3];
    const float* aux   = (const float*)d_in[4];
    const float* taux  = (const float*)d_in[5];
    const float* sigma = (const float*)d_in[6];
    float* out = (float*)d_out;

    const int B = in_sizes[2] / 13;
    double* gacc = (double*)d_ws;   // 5*SLOTS doubles = 2560 B

    const int geoBlocks  = (B + GROWS - 1) / GROWS;
    const long long maskTasks = (long long)B * 13;
    const int maskBlocks = (int)((maskTasks + MTASKS - 1) / MTASKS);
    const int totalBlocks = geoBlocks + maskBlocks;

    hipLaunchKernelGGL(zero_acc, dim3(1), dim3(512), 0, stream, gacc);
    hipLaunchKernelGGL(loss_fused, dim3(totalBlocks), dim3(THREADS), 0, stream,
                       geo, mgo, pos, mgt, gacc, B, geoBlocks, tb);
    hipLaunchKernelGGL(finalize, dim3(1), dim3(64), 0, stream,
                       gacc, aux, taux, sigma, out, (double)B * 12.0);
}

// Round 2
// 441.336 us; speedup vs baseline: 1.0123x; 1.0123x over previous
//
#include <hip/hip_runtime.h>
#include <cmath>

#define THREADS 256
#define TASKS   192   // compute tasks per block = exactly 3 full waves
#define GROWS   16    // geo rows per block: 16*12 = 192 tasks, 16*1584 B = 25344 B LDS
#define MTASKS  192   // mask tasks per block: 192*132 B = 25344 B LDS (same buffer)
#define SLOTS   64    // accumulator spreading to avoid same-address atomic serialization

struct Tables { float cont[13]; float cw[12]; float ew[12]; };

static Tables make_tables() {
    Tables tb;
    tb.cont[0] = 0.0f;
    for (int j = 1; j <= 12; j++) {
        // numpy: x = linspace(0, b, 2000) (step b/1999), dx = b/2000
        double b = (double)j;
        double s = 0.0;
        for (int k = 0; k < 2000; k++) {
            double x = b * (double)k / 1999.0;
            s += pow(0.8, x);
        }
        double integ = s * (b / 2000.0);
        tb.cont[j] = (float)(1.0 / integ);
    }
    for (int s = 0; s < 12; s++) {
        double w = pow(0.8, (double)s);
        tb.cw[s] = (float)w;
        tb.ew[s] = (float)(w + 1.0);
    }
    return tb;
}

__global__ void zero_acc(double* g) {
    int t = threadIdx.x;
    if (t < 5 * SLOTS) g[t] = 0.0;
}

// CK-style generic->LDS address-space cast (low 32 bits of a generic LDS
// pointer are the LDS offset on gfx9+)
typedef __attribute__((address_space(3))) unsigned int* LdsPtr;
typedef const __attribute__((address_space(1))) unsigned int* GblPtr;
__device__ __forceinline__ LdsPtr to_lds(const void* p) {
    return (LdsPtr)(unsigned int)(unsigned long long)p;
}

// LDS: buf 25344 + s_ce 768 + s_corr 768 + tables 148 + red 48 ≈ 27.1 KB
// → 32 KiB granule → 5 blocks/CU (occupancy proved non-binding in R1).
// launch_bounds min-5-waves/EU → VGPR cap ~102: room for xv[33] in registers.
__global__ __launch_bounds__(THREADS, 5) void loss_fused(
    const float* __restrict__ geo,   // (B,12,33)
    const float* __restrict__ mgo,   // (B,13,33)
    const int*   __restrict__ pos,   // (B,13)
    const int*   __restrict__ mgt,   // (B,13)
    double*      __restrict__ gacc,  // 5 * SLOTS doubles
    int B, int geoBlocks, Tables tb)
{
    __shared__ float buf[TASKS * 33];      // 25344 B, shared by both block types
    __shared__ float s_ce[TASKS];
    __shared__ int   s_corr[TASKS];
    __shared__ float sh_cont[13];
    __shared__ float sh_cw[12];
    __shared__ float sh_ew[12];
    __shared__ float red[4][3];

    const int t = threadIdx.x;
    const int wid = t >> 6, lane = t & 63;
    float v0 = 0.0f, v1 = 0.0f, v2 = 0.0f;
    const bool isGeo = (blockIdx.x < (unsigned)geoBlocks);

    if (isGeo) {
        const long long row0 = (long long)blockIdx.x * GROWS;
        const int nrows = min(GROWS, (int)(B - row0));
        const int ntask = nrows * 12;
        const int r = t / 12, s = t - (t / 12) * 12;
        // hoist target load above staging: global latency overlaps the DMA issue
        int tg = 0;
        if (t < ntask) tg = pos[(row0 + r) * 13 + s + 1];
        if (t == 0) {   // tables to LDS, static indices only
            #pragma unroll
            for (int j = 0; j < 13; j++) sh_cont[j] = tb.cont[j];
            #pragma unroll
            for (int j = 0; j < 12; j++) { sh_cw[j] = tb.cw[j]; sh_ew[j] = tb.ew[j]; }
        }
        {   // stage nrows*1584 B via global->LDS DMA (1584 = 99*16, always 16B-mult)
            // dest: wave-uniform base + lane*16 == linear layout. src 16B-aligned.
            const float* src = geo + row0 * 396;
            const int nf16 = nrows * 99;                 // 16B chunks
            for (int c = wid * 64; c < nf16; c += 256) { // c wave-uniform
                const int idx = c + lane;
                if (idx < nf16)
                    __builtin_amdgcn_global_load_lds((GblPtr)(src + idx * 4),
                                                     to_lds(buf + c * 4), 16, 0, 0);
            }
        }
        __syncthreads();   // drains vmcnt (DMA) + lgkmcnt

        if (t < ntask) {
            const int base = t * 33;   // stride 33 ≡ 1 (mod 32): bank-conflict-free
            float xv[33];
            #pragma unroll
            for (int k = 0; k < 33; k++) xv[k] = buf[base + k];
            // max via 4-accumulator fmax tree (no argmax tracking needed)
            float m0 = fmaxf(xv[0], xv[1]), m1 = fmaxf(xv[2], xv[3]);
            float m2 = fmaxf(xv[4], xv[5]), m3 = fmaxf(xv[6], xv[7]);
            #pragma unroll
            for (int k = 8; k < 32; k += 4) {
                m0 = fmaxf(m0, xv[k]);     m1 = fmaxf(m1, xv[k + 1]);
                m2 = fmaxf(m2, xv[k + 2]); m3 = fmaxf(m3, xv[k + 3]);
            }
            const float m = fmaxf(fmaxf(fmaxf(m0, m1), fmaxf(m2, m3)), xv[32]);
            float p0 = 0, p1 = 0, p2 = 0, p3 = 0;
            #pragma unroll
            for (int k = 0; k < 32; k += 4) {
                p0 += __expf(xv[k] - m);     p1 += __expf(xv[k + 1] - m);
                p2 += __expf(xv[k + 2] - m); p3 += __expf(xv[k + 3] - m);
            }
            const float sum = (p0 + p1) + (p2 + p3) + __expf(xv[32] - m);
            const float lse = __logf(sum) + m;
            const int tc = tg < 0 ? 0 : (tg > 32 ? 32 : tg);
            const float xtc = buf[base + tc];      // one dynamic LDS read
            const float ce = (tg == 32) ? 0.0f : (lse - xtc);  // ignore_index = 32
            // correct ⟺ x[tg] attains the max (first-tie semantics: ties are
            // measure-zero on random float inputs)
            const int corr = (tg == tc && xtc == m) ? 1 : 0;
            v1 = corr ? ce * sh_cw[s] : 0.0f;
            v2 = corr ? 0.0f : ce * sh_ew[s];
            s_ce[t] = ce;
            s_corr[t] = corr;
        }
        __syncthreads();

        // per-row prefix: first-incorrect index + weighted prefix sum
        if (t < nrows) {
            float ps = 0.0f; int mi = 12;
            for (int s2 = 0; s2 < 12; s2++) {
                if (!s_corr[t * 12 + s2]) { mi = s2; break; }
                ps += s_ce[t * 12 + s2];
            }
            v0 = (mi >= 12) ? 0.0f : ps * sh_cont[mi];
        }
    } else {
        const long long totalTasks = (long long)B * 13;
        const long long base = (long long)(blockIdx.x - geoBlocks) * MTASKS;
        const int cnt = (int)min((long long)MTASKS, totalTasks - base);
        int tg = 0;
        if (t < cnt) tg = mgt[base + t];
        {   // stage cnt*132 B; DMA the 16B-multiple part, scalar tail (cnt%4 != 0 only
            // possible in the last block). src base: blk*25344 B -> 16B aligned.
            const float* src = mgo + base * 33;
            const int nfl = cnt * 33;
            const int nf16 = nfl >> 2;
            for (int c = wid * 64; c < nf16; c += 256) {
                const int idx = c + lane;
                if (idx < nf16)
                    __builtin_amdgcn_global_load_lds((GblPtr)(src + idx * 4),
                                                     to_lds(buf + c * 4), 16, 0, 0);
            }
            for (int i = (nf16 << 2) + t; i < nfl; i += THREADS) buf[i] = src[i];
        }
        __syncthreads();

        if (t < cnt) {
            const int base2 = t * 33;
            float xv[33];
            #pragma unroll
            for (int k = 0; k < 33; k++) xv[k] = buf[base2 + k];
            float m0 = fmaxf(xv[0], xv[1]), m1 = fmaxf(xv[2], xv[3]);
            float m2 = fmaxf(xv[4], xv[5]), m3 = fmaxf(xv[6], xv[7]);
            #pragma unroll
            for (int k = 8; k < 32; k += 4) {
                m0 = fmaxf(m0, xv[k]);     m1 = fmaxf(m1, xv[k + 1]);
                m2 = fmaxf(m2, xv[k + 2]); m3 = fmaxf(m3, xv[k + 3]);
            }
            const float m = fmaxf(fmaxf(fmaxf(m0, m1), fmaxf(m2, m3)), xv[32]);
            float p0 = 0, p1 = 0, p2 = 0, p3 = 0;
            #pragma unroll
            for (int k = 0; k < 32; k += 4) {
                p0 += __expf(xv[k] - m);     p1 += __expf(xv[k + 1] - m);
                p2 += __expf(xv[k + 2] - m); p3 += __expf(xv[k + 3] - m);
            }
            const float sum = (p0 + p1) + (p2 + p3) + __expf(xv[32] - m);
            const float lse = __logf(sum) + m;
            const int tc = tg < 0 ? 0 : (tg > 32 ? 32 : tg);
            const float xtc = buf[base2 + tc];
            if (tg != -100) { v0 = lse - xtc; v1 = 1.0f; }
        }
    }

    // block reduction: wave64 shuffle then cross-wave via LDS
    #pragma unroll
    for (int off = 32; off; off >>= 1) {
        v0 += __shfl_down(v0, off, 64);
        v1 += __shfl_down(v1, off, 64);
        v2 += __shfl_down(v2, off, 64);
    }
    if (lane == 0) { red[wid][0] = v0; red[wid][1] = v1; red[wid][2] = v2; }
    __syncthreads();
    if (t == 0) {
        float a0 = 0, a1 = 0, a2 = 0;
        for (int w = 0; w < 4; w++) { a0 += red[w][0]; a1 += red[w][1]; a2 += red[w][2]; }
        const int slot = blockIdx.x & (SLOTS - 1);
        if (isGeo) {
            atomicAdd(&gacc[2 * SLOTS + slot], (double)a0);
            atomicAdd(&gacc[3 * SLOTS + slot], (double)a1);
            atomicAdd(&gacc[4 * SLOTS + slot], (double)a2);
        } else {
            atomicAdd(&gacc[0 * SLOTS + slot], (double)a0);
            atomicAdd(&gacc[1 * SLOTS + slot], (double)a1);
        }
    }
}

__global__ void finalize(const double* __restrict__ g,
                         const float* __restrict__ aux,
                         const float* __restrict__ taux,
                         const float* __restrict__ sigma,
                         float* __restrict__ out, double denom)
{
    const int i = threadIdx.x;   // 64 threads
    double a[5];
    #pragma unroll
    for (int q = 0; q < 5; q++) a[q] = g[q * SLOTS + i];
    #pragma unroll
    for (int off = 32; off; off >>= 1) {
        #pragma unroll
        for (int q = 0; q < 5; q++) a[q] += __shfl_down(a[q], off, 64);
    }
    if (i == 0) {
        double mask_loss = a[0] / fmax(a[1], 1.0);
        double prefix = a[2] / denom, corrL = a[3] / denom, errL = a[4] / denom;
        double geoL = prefix + corrL + errL;
        double L[4] = { geoL, mask_loss, (double)aux[0], (double)taux[0] };
        double wsum = 0.0, prod = 1.0;
        for (int q = 0; q < 4; q++) {
            double sg = (double)sigma[q];
            wsum += 0.5 * L[q] / (sg * sg);
            prod *= sg;
        }
        wsum += log(prod);
        out[0] = (float)wsum;
        out[1] = (float)prefix;
        out[2] = (float)corrL;
        out[3] = (float)errL;
        out[4] = (float)mask_loss;
    }
}

extern "C" void kernel_launch(void* const* d_in, const int* in_sizes, int n_in,
                              void* d_out, int out_size, void* d_ws, size_t ws_size,
                              hipStream_t stream)
{
    static Tables tb = make_tables();   // host-only, graph-capture safe

    const float* geo   = (const float*)d_in[0];
    const float* mgo   = (const float*)d_in[1];
    const int*   pos   = (const int*)d_in[2];
    const int*   mgt   = (const int*)d_in[3];
    const float* aux   = (const float*)d_in[4];
    const float* taux  = (const float*)d_in[5];
    const float* sigma = (const float*)d_in[6];
    float* out = (float*)d_out;

    const int B = in_sizes[2] / 13;
    double* gacc = (double*)d_ws;   // 5*SLOTS doubles = 2560 B

    const int geoBlocks  = (B + GROWS - 1) / GROWS;
    const long long maskTasks = (long long)B * 13;
    const int maskBlocks = (int)((maskTasks + MTASKS - 1) / MTASKS);
    const int totalBlocks = geoBlocks + maskBlocks;

    hipLaunchKernelGGL(zero_acc, dim3(1), dim3(512), 0, stream, gacc);
    hipLaunchKernelGGL(loss_fused, dim3(totalBlocks), dim3(THREADS), 0, stream,
                       geo, mgo, pos, mgt, gacc, B, geoBlocks, tb);
    hipLaunchKernelGGL(finalize, dim3(1), dim3(64), 0, stream,
                       gacc, aux, taux, sigma, out, (double)B * 12.0);
}